// Round 5
// baseline (504.399 us; speedup 1.0000x reference)
//
#include <hip/hip_runtime.h>
#include <hip/hip_bf16.h>

// Problem constants
#define BS 8
#define NN 64
#define HD 512
#define NLAYER 5
// Inputs fp32, output fp32 (128 MB). bf16 internally for MFMA.
// Big scratch lives in d_out (~108 MB of 134 MB); ws holds nodef + denom only.

typedef short bf16x8 __attribute__((ext_vector_type(8)));
typedef float f32x4 __attribute__((ext_vector_type(4)));

__device__ __forceinline__ float lrelu(float x) { return x > 0.f ? x : 0.01f * x; }

__device__ __forceinline__ void cp16(const void* g, void* l) {
    __builtin_amdgcn_global_load_lds(
        (const __attribute__((address_space(1))) unsigned int*)g,
        (__attribute__((address_space(3))) unsigned int*)l,
        16, 0, 0);
}

// ---------------------------------------------------------------------------
// prep (fused wcvt + node init + edge_init + denom):
__global__ __launch_bounds__(256) void prep_kernel(
    const float* __restrict__ roi, const float* __restrict__ img,
    const float* __restrict__ nW, const float* __restrict__ eW,
    const int* __restrict__ mask,
    __hip_bfloat16* __restrict__ nWb, __hip_bfloat16* __restrict__ eWb,
    float* __restrict__ nodef, __hip_bfloat16* __restrict__ nodeb,
    float* __restrict__ edge_init, float* __restrict__ denom)
{
    int bid = blockIdx.x, tid = threadIdx.x;
    if (bid < 2560) {
        const float* src = (bid < 1280) ? nW : eW;
        __hip_bfloat16* dst = (bid < 1280) ? nWb : eWb;
        int base = ((bid < 1280) ? bid : bid - 1280) * 1024 + tid * 4;
#pragma unroll
        for (int k = 0; k < 4; ++k) dst[base + k] = __float2bfloat16(src[base + k]);
    } else if (bid < 2816) {
        int base = (bid - 2560) * 1024 + tid * 4;
#pragma unroll
        for (int k = 0; k < 4; ++k) {
            float v = roi[base + k];
            nodef[base + k] = v;
            nodeb[base + k] = __float2bfloat16(v);
        }
    } else if (bid < 3840) {
        int pid = (bid - 2816) * 4 + (tid >> 6);   // (b*512+h), 0..4095
        int l = tid & 63;
        const float* p = img + (size_t)pid * 196;
        float s = 0.f;
        for (int x = l; x < 196; x += 64) s += p[x];
#pragma unroll
        for (int off = 1; off < 64; off <<= 1) s += __shfl_xor(s, off, 64);
        if (l == 0) edge_init[pid] = s * (1.f / 196.f);
    } else {
        int pid = (bid - 3840) * 256 + tid;       // 0..511
        if (pid < 512) {
            const int* m = mask + pid * 64;
            int s = 0;
#pragma unroll
            for (int j = 0; j < 64; ++j) s += m[j];
            denom[pid] = (float)s + 1.f;
        }
    }
}

// ---------------------------------------------------------------------------
// em0: one wave per (b,o). Coalesced float4 loads of eW0 row, shuffle-reduce.
__global__ __launch_bounds__(256) void em0_kernel(
    const float* __restrict__ edge_init,
    const float* __restrict__ eW0,
    const float* __restrict__ eB0,
    float* __restrict__ em0)
{
    int W = blockIdx.x * 4 + (threadIdx.x >> 6);  // 0..4095
    int l = threadIdx.x & 63;
    int b = W >> 9, o = W & 511;
    const float4* ei = (const float4*)(edge_init + b * 512);
    const float4* w4 = (const float4*)(eW0 + (size_t)o * 512);
    float4 a0 = ei[l * 2], a1 = ei[l * 2 + 1];
    float4 b0 = w4[l * 2], b1 = w4[l * 2 + 1];
    float s = a0.x * b0.x + a0.y * b0.y + a0.z * b0.z + a0.w * b0.w
            + a1.x * b1.x + a1.y * b1.y + a1.z * b1.z + a1.w * b1.w;
#pragma unroll
    for (int off = 1; off < 64; off <<= 1) s += __shfl_xor(s, off, 64);
    if (l == 0) em0[W] = s + eB0[o];
}

// ---------------------------------------------------------------------------
// nm GEMM: nm[r][o] = sum_h node_bf16[r][h] * W[o][h] + bias[o]  (512x512x512)
// BM=32, BN=64, BK=64 -> grid (16,8) = 128 blocks, 8 K-steps, 12 KB LDS.
__global__ __launch_bounds__(256, 4) void nm_gemm(
    const __hip_bfloat16* __restrict__ A,   // 512x512 node bf16
    const __hip_bfloat16* __restrict__ W,   // 512x512 (o,h) bf16
    const float* __restrict__ bias,
    float* __restrict__ nm)
{
    __shared__ __align__(16) __hip_bfloat16 sA[32 * 64];   // 4 KB
    __shared__ __align__(16) __hip_bfloat16 sB[64 * 64];   // 8 KB
    int tid = threadIdx.x;
    int bm = blockIdx.x, bn = blockIdx.y;   // bm 0..15, bn 0..7
    int w = tid >> 6, l = tid & 63;
    int wm = w & 1, wn = w >> 1;
    int lq = l >> 4, lr = l & 15;

    const char* aBase = (const char*)A + (size_t)bm * 32 * 1024;  // row 1024B
    const char* bBase = (const char*)W + (size_t)bn * 64 * 1024;
    int rowA = tid >> 3;
    int gA = rowA * 1024 + (((tid & 7) ^ (rowA & 7)) << 4);
    int lO = tid * 16;
    int sw = lr & 7;

    f32x4 acc[2] = {};

    for (int kt = 0; kt < 8; ++kt) {
        int ko = kt * 128;
        cp16(aBase + gA + ko, (char*)sA + lO);
        cp16(bBase + gA + ko, (char*)sB + lO);            // B rows 0..31
        cp16(bBase + gA + 32768 + ko, (char*)sB + lO + 4096); // B rows 32..63
        __syncthreads();
#pragma unroll
        for (int kk = 0; kk < 2; ++kk) {
            bf16x8 af = *(const bf16x8*)&sA[(wm * 16 + lr) * 64 + (((kk * 4 + lq) ^ sw) << 3)];
#pragma unroll
            for (int ni = 0; ni < 2; ++ni) {
                bf16x8 bv = *(const bf16x8*)&sB[(wn * 32 + ni * 16 + lr) * 64 + (((kk * 4 + lq) ^ sw) << 3)];
                acc[ni] = __builtin_amdgcn_mfma_f32_16x16x32_bf16(af, bv, acc[ni], 0, 0, 0);
            }
        }
        __syncthreads();
    }
#pragma unroll
    for (int ni = 0; ni < 2; ++ni) {
        int col = bn * 64 + wn * 32 + ni * 16 + lr;
        float bv = bias[col];
#pragma unroll
        for (int r = 0; r < 4; ++r) {
            int row = bm * 32 + wm * 16 + lq * 4 + r;
            nm[(size_t)row * 512 + col] = acc[ni][r] + bv;
        }
    }
}

// ---------------------------------------------------------------------------
// t=0: es = lrelu(nm_i + nm_j + em0_b), write es, agg -> fused node update
__global__ __launch_bounds__(256) void edge_rank1(
    const float* __restrict__ nm, const float* __restrict__ em0,
    const int* __restrict__ mask,
    __hip_bfloat16* __restrict__ es_dst,
    const float* __restrict__ denom,
    float* __restrict__ nodef, __hip_bfloat16* __restrict__ nodeb)
{
    int g = blockIdx.x >> 1, ch = blockIdx.x & 1;
    int c = ch * 256 + threadIdx.x;
    int b = g >> 6;
    float nmi = nm[(size_t)g * 512 + c];          // raw nm[g][c]
    float emb = em0[b * 512 + c];
    const float* nmb = nm + (size_t)b * 64 * 512;
    const int* mrow = mask + g * 64;
    __hip_bfloat16* erow = es_dst + (size_t)g * 64 * 512 + c;
    float aggv = 0.f;
#pragma unroll 4
    for (int j = 0; j < 64; ++j) {
        float nmj = nmb[j * 512 + c];
        float es = lrelu(nmi + nmj + emb);
        erow[(size_t)j * 512] = __float2bfloat16(es);
        aggv += es * nmj * (float)mrow[j];
    }
    float nf = (nmi + aggv) / denom[g];
    size_t idx = (size_t)g * 512 + c;
    float ns = nodef[idx] + lrelu(nf);
    nodef[idx] = ns;
    nodeb[idx] = __float2bfloat16(ns);
}

// ---------------------------------------------------------------------------
// em_gemm (t>=1): em[r][c] = sum_h es_src[r][h] * eW[c][h]  (32768x512x512)
// Structure for small-K: the 64-col x K=512 B-panel (64 KB) is staged in LDS
// ONCE per block (XOR-swizzled via pre-swizzled source, linear dest — rule
// #21), with a single barrier. The K-loop then has NO barriers and NO LDS
// staging: each wave streams its 32 A-rows from global directly into MFMA
// fragments (per instr: 16 rows x 64 B, fully-used lines) and reads B-frags
// from LDS. This removes the per-K-step drain chain entirely — the variable
// all 5 previous rounds failed to move.
__global__ __launch_bounds__(256, 2) void em_gemm(
    const __hip_bfloat16* __restrict__ es_src,   // 32768 x 512 bf16
    const __hip_bfloat16* __restrict__ eW,       // 512 x 512 bf16 (o,h)
    __hip_bfloat16* __restrict__ em)             // 32768 x 512 bf16 (no bias)
{
    __shared__ __align__(16) __hip_bfloat16 sB[64 * 512];   // 64 KB
    int tid = threadIdx.x;
    int bn = blockIdx.x;          // 0..7  (64-col tile)
    int bm = blockIdx.y;          // 0..255 (128-row tile)
    int wv = tid >> 6, l = tid & 63;
    int lq = l >> 4, lr = l & 15;

    // --- stage B panel (contiguous 65536 B of eW), one barrier ---
    const char* bBase = (const char*)eW + (size_t)bn * 65536;
#pragma unroll
    for (int i = 0; i < 16; ++i) {
        int chunk = tid + i * 256;                 // 0..4095 (row=chunk>>6, c16=chunk&63)
        int srcOff = (chunk & ~63) * 16 + (((chunk & 63) ^ ((chunk >> 6) & 7)) << 4);
        cp16(bBase + srcOff, (char*)sB + chunk * 16);
    }
    __syncthreads();   // single full drain per block — acceptable (once)

    // --- barrier-free K-loop: A from global, B from LDS ---
    int rbase = bm * 128 + wv * 32;
    const char* aBase = (const char*)es_src + (size_t)rbase * 1024;
    const char* sBb = (const char*)sB;

    f32x4 acc[2][4] = {};
#pragma unroll
    for (int kq = 0; kq < 16; ++kq) {
        bf16x8 a0 = *(const bf16x8*)(aBase + lr * 1024 + kq * 64 + lq * 16);
        bf16x8 a1 = *(const bf16x8*)(aBase + (16 + lr) * 1024 + kq * 64 + lq * 16);
#pragma unroll
        for (int cg = 0; cg < 4; ++cg) {
            int rl = cg * 16 + lr;
            bf16x8 bf = *(const bf16x8*)(sBb + rl * 1024 + ((((kq * 4 + lq) ^ (rl & 7))) << 4));
            acc[0][cg] = __builtin_amdgcn_mfma_f32_16x16x32_bf16(a0, bf, acc[0][cg], 0, 0, 0);
            acc[1][cg] = __builtin_amdgcn_mfma_f32_16x16x32_bf16(a1, bf, acc[1][cg], 0, 0, 0);
        }
    }

    // --- store (bf16, no bias; epilogue adds eB) ---
#pragma unroll
    for (int rg = 0; rg < 2; ++rg)
#pragma unroll
        for (int cg = 0; cg < 4; ++cg)
#pragma unroll
            for (int r = 0; r < 4; ++r) {
                int row = rbase + rg * 16 + lq * 4 + r;
                int col = bn * 64 + cg * 16 + lr;
                em[(size_t)row * 512 + col] = __float2bfloat16(acc[rg][cg][r]);
            }
}

// ---------------------------------------------------------------------------
// edge_ep (t>=1): rank1-style epilogue reading em.
// es = lrelu(em + (nm_i + eB) + nm_j); agg; node update. Thread owns (g,c).
__global__ __launch_bounds__(256) void edge_ep(
    const __hip_bfloat16* __restrict__ em,       // 32768 x 512 bf16
    const float* __restrict__ nm,                // 512 x 512 fp32
    const float* __restrict__ eB,                // 512 fp32
    const int* __restrict__ mask,
    __hip_bfloat16* __restrict__ es_dst,
    const float* __restrict__ denom,
    float* __restrict__ nodef, __hip_bfloat16* __restrict__ nodeb,
    int write_es)
{
    int g = blockIdx.x >> 1, ch = blockIdx.x & 1;
    int c = ch * 256 + threadIdx.x;
    int b = g >> 6;
    float nmraw = nm[(size_t)g * 512 + c];
    float nmi = nmraw + eB[c];
    const __hip_bfloat16* emrow = em + (size_t)g * 64 * 512 + c;
    const float* nmb = nm + (size_t)b * 64 * 512;
    const int* mrow = mask + g * 64;
    __hip_bfloat16* erow = es_dst + (size_t)g * 64 * 512 + c;
    float aggv = 0.f;
#pragma unroll 4
    for (int j = 0; j < 64; ++j) {
        float emv = __bfloat162float(emrow[(size_t)j * 512]);
        float nmj = nmb[j * 512 + c];
        float es = lrelu(emv + nmi + nmj);
        if (write_es) erow[(size_t)j * 512] = __float2bfloat16(es);
        aggv += es * nmj * (float)mrow[j];
    }
    float nf = (nmraw + aggv) / denom[g];
    size_t idx = (size_t)g * 512 + c;
    float ns = nodef[idx] + lrelu(nf);
    nodef[idx] = ns;
    nodeb[idx] = __float2bfloat16(ns);
}

// ---------------------------------------------------------------------------
// out (fp32): out[b,i,j,0:512]=node[b,i,:], [512:1024]=node[b,j,:]
__global__ __launch_bounds__(256) void out_kernel(
    const float* __restrict__ nodef, float* __restrict__ out)
{
    size_t ch = (size_t)blockIdx.x * 256 + threadIdx.x;  // 16B chunk id
    int c4 = (int)(ch & 255);
    size_t r = ch >> 8;                // (b*64+i)*64 + j
    int b = (int)(r >> 12);
    int i = (int)((r >> 6) & 63);
    int j = (int)(r & 63);
    int c = c4 * 4;
    const float* src = (c < 512) ? (nodef + ((size_t)(b * 64 + i)) * 512 + c)
                                 : (nodef + ((size_t)(b * 64 + j)) * 512 + (c - 512));
    *reinterpret_cast<float4*>(out + ch * 4) = *reinterpret_cast<const float4*>(src);
}

// ---------------------------------------------------------------------------
extern "C" void kernel_launch(void* const* d_in, const int* in_sizes, int n_in,
                              void* d_out, int out_size, void* d_ws, size_t ws_size,
                              hipStream_t stream) {
    const float* roi  = (const float*)d_in[0];
    const float* img  = (const float*)d_in[1];
    const float* nW   = (const float*)d_in[2];
    const float* nB   = (const float*)d_in[3];
    const float* eW   = (const float*)d_in[4];
    const float* eB   = (const float*)d_in[5];
    const int*   mask = (const int*)d_in[6];

    // Large scratch inside d_out (134 MB); all dead before out_kernel rewrites.
    char* ob = (char*)d_out;
    const size_t ES_BYTES = (size_t)32768 * 512 * 2;            // 33,554,432
    __hip_bfloat16* es0   = (__hip_bfloat16*)(ob);
    __hip_bfloat16* es1   = (__hip_bfloat16*)(ob + ES_BYTES);
    __hip_bfloat16* emb   = (__hip_bfloat16*)(ob + 2 * ES_BYTES);              // 33.5MB
    __hip_bfloat16* eWb   = (__hip_bfloat16*)(ob + 3 * ES_BYTES);              // 2.62MB
    __hip_bfloat16* nWb   = (__hip_bfloat16*)(ob + 3 * ES_BYTES + 2621440);    // 2.62MB
    __hip_bfloat16* nodeb = (__hip_bfloat16*)(ob + 3 * ES_BYTES + 5242880);    // 0.5MB
    float*          nm    = (float*)(ob + 3 * ES_BYTES + 5767168);             // 1MB
    float*       edge_init= (float*)(ob + 3 * ES_BYTES + 6815744);             // 16KB
    float*          em0   = (float*)(ob + 3 * ES_BYTES + 6832128);             // 16KB

    char* ws = (char*)d_ws;
    float* nodef = (float*)(ws);                 // 1MB
    float* denom = (float*)(ws + 1048576);       // 2KB
    float* outp  = (float*)d_out;

    prep_kernel<<<3842, 256, 0, stream>>>(roi, img, nW, eW, mask,
                                          nWb, eWb, nodef, nodeb, edge_init, denom);
    em0_kernel<<<1024, 256, 0, stream>>>(edge_init, eW, eB, em0);

    // t = 0
    nm_gemm<<<dim3(16, 8), 256, 0, stream>>>(nodeb, nWb, nB, nm);
    edge_rank1<<<1024, 256, 0, stream>>>(nm, em0, mask, es0, denom, nodef, nodeb);

    // t = 1..4
    for (int t = 1; t < NLAYER; ++t) {
        const __hip_bfloat16* src = (t & 1) ? es0 : es1;
        __hip_bfloat16* dst       = (t & 1) ? es1 : es0;
        nm_gemm<<<dim3(16, 8), 256, 0, stream>>>(nodeb, nWb + (size_t)t * 262144,
                                                 nB + t * 512, nm);
        em_gemm<<<dim3(8, 256), 256, 0, stream>>>(src, eWb + (size_t)t * 262144, emb);
        edge_ep<<<1024, 256, 0, stream>>>(emb, nm, eB + t * 512, mask,
                                          dst, denom, nodef, nodeb,
                                          (t < 4) ? 1 : 0);
    }

    out_kernel<<<32768, 256, 0, stream>>>(nodef, outp);
}

// Round 6
// 361.134 us; speedup vs baseline: 1.3967x; 1.3967x over previous
//
#include <hip/hip_runtime.h>
#include <hip/hip_bf16.h>

// Problem constants
#define BS 8
#define NN 64
#define HD 512
#define NLAYER 5
// Inputs fp32, output fp32 (128 MB). bf16 internally for MFMA.
// Big scratch lives in d_out; ws holds nodef + denom only.

typedef short bf16x8 __attribute__((ext_vector_type(8)));
typedef float f32x4 __attribute__((ext_vector_type(4)));

__device__ __forceinline__ float lrelu(float x) { return x > 0.f ? x : 0.01f * x; }

__device__ __forceinline__ void cp16(const void* g, void* l) {
    __builtin_amdgcn_global_load_lds(
        (const __attribute__((address_space(1))) unsigned int*)g,
        (__attribute__((address_space(3))) unsigned int*)l,
        16, 0, 0);
}

// ---------------------------------------------------------------------------
// prep (fused wcvt + node init + edge_init + denom):
__global__ __launch_bounds__(256) void prep_kernel(
    const float* __restrict__ roi, const float* __restrict__ img,
    const float* __restrict__ nW, const float* __restrict__ eW,
    const int* __restrict__ mask,
    __hip_bfloat16* __restrict__ nWb, __hip_bfloat16* __restrict__ eWb,
    float* __restrict__ nodef, __hip_bfloat16* __restrict__ nodeb,
    float* __restrict__ edge_init, float* __restrict__ denom)
{
    int bid = blockIdx.x, tid = threadIdx.x;
    if (bid < 2560) {
        const float* src = (bid < 1280) ? nW : eW;
        __hip_bfloat16* dst = (bid < 1280) ? nWb : eWb;
        int base = ((bid < 1280) ? bid : bid - 1280) * 1024 + tid * 4;
#pragma unroll
        for (int k = 0; k < 4; ++k) dst[base + k] = __float2bfloat16(src[base + k]);
    } else if (bid < 2816) {
        int base = (bid - 2560) * 1024 + tid * 4;
#pragma unroll
        for (int k = 0; k < 4; ++k) {
            float v = roi[base + k];
            nodef[base + k] = v;
            nodeb[base + k] = __float2bfloat16(v);
        }
    } else if (bid < 3840) {
        int pid = (bid - 2816) * 4 + (tid >> 6);   // (b*512+h), 0..4095
        int l = tid & 63;
        const float* p = img + (size_t)pid * 196;
        float s = 0.f;
        for (int x = l; x < 196; x += 64) s += p[x];
#pragma unroll
        for (int off = 1; off < 64; off <<= 1) s += __shfl_xor(s, off, 64);
        if (l == 0) edge_init[pid] = s * (1.f / 196.f);
    } else {
        int pid = (bid - 3840) * 256 + tid;       // 0..511
        if (pid < 512) {
            const int* m = mask + pid * 64;
            int s = 0;
#pragma unroll
            for (int j = 0; j < 64; ++j) s += m[j];
            denom[pid] = (float)s + 1.f;
        }
    }
}

// ---------------------------------------------------------------------------
// em0: one wave per (b,o). Coalesced float4 loads of eW0 row, shuffle-reduce.
__global__ __launch_bounds__(256) void em0_kernel(
    const float* __restrict__ edge_init,
    const float* __restrict__ eW0,
    const float* __restrict__ eB0,
    float* __restrict__ em0)
{
    int W = blockIdx.x * 4 + (threadIdx.x >> 6);  // 0..4095
    int l = threadIdx.x & 63;
    int b = W >> 9, o = W & 511;
    const float4* ei = (const float4*)(edge_init + b * 512);
    const float4* w4 = (const float4*)(eW0 + (size_t)o * 512);
    float4 a0 = ei[l * 2], a1 = ei[l * 2 + 1];
    float4 b0 = w4[l * 2], b1 = w4[l * 2 + 1];
    float s = a0.x * b0.x + a0.y * b0.y + a0.z * b0.z + a0.w * b0.w
            + a1.x * b1.x + a1.y * b1.y + a1.z * b1.z + a1.w * b1.w;
#pragma unroll
    for (int off = 1; off < 64; off <<= 1) s += __shfl_xor(s, off, 64);
    if (l == 0) em0[W] = s + eB0[o];
}

// ---------------------------------------------------------------------------
// nm GEMM: nm[r][o] = sum_h node_bf16[r][h] * W[o][h] + bias[o]  (512x512x512)
// BM=32, BN=64, BK=64 -> grid (16,8) = 128 blocks, 8 K-steps, 12 KB LDS.
__global__ __launch_bounds__(256, 4) void nm_gemm(
    const __hip_bfloat16* __restrict__ A,   // 512x512 node bf16
    const __hip_bfloat16* __restrict__ W,   // 512x512 (o,h) bf16
    const float* __restrict__ bias,
    float* __restrict__ nm)
{
    __shared__ __align__(16) __hip_bfloat16 sA[32 * 64];   // 4 KB
    __shared__ __align__(16) __hip_bfloat16 sB[64 * 64];   // 8 KB
    int tid = threadIdx.x;
    int bm = blockIdx.x, bn = blockIdx.y;   // bm 0..15, bn 0..7
    int w = tid >> 6, l = tid & 63;
    int wm = w & 1, wn = w >> 1;
    int lq = l >> 4, lr = l & 15;

    const char* aBase = (const char*)A + (size_t)bm * 32 * 1024;  // row 1024B
    const char* bBase = (const char*)W + (size_t)bn * 64 * 1024;
    int rowA = tid >> 3;
    int gA = rowA * 1024 + (((tid & 7) ^ (rowA & 7)) << 4);
    int lO = tid * 16;
    int sw = lr & 7;

    f32x4 acc[2] = {};

    for (int kt = 0; kt < 8; ++kt) {
        int ko = kt * 128;
        cp16(aBase + gA + ko, (char*)sA + lO);
        cp16(bBase + gA + ko, (char*)sB + lO);            // B rows 0..31
        cp16(bBase + gA + 32768 + ko, (char*)sB + lO + 4096); // B rows 32..63
        __syncthreads();
#pragma unroll
        for (int kk = 0; kk < 2; ++kk) {
            bf16x8 af = *(const bf16x8*)&sA[(wm * 16 + lr) * 64 + (((kk * 4 + lq) ^ sw) << 3)];
#pragma unroll
            for (int ni = 0; ni < 2; ++ni) {
                bf16x8 bv = *(const bf16x8*)&sB[(wn * 32 + ni * 16 + lr) * 64 + (((kk * 4 + lq) ^ sw) << 3)];
                acc[ni] = __builtin_amdgcn_mfma_f32_16x16x32_bf16(af, bv, acc[ni], 0, 0, 0);
            }
        }
        __syncthreads();
    }
#pragma unroll
    for (int ni = 0; ni < 2; ++ni) {
        int col = bn * 64 + wn * 32 + ni * 16 + lr;
        float bv = bias[col];
#pragma unroll
        for (int r = 0; r < 4; ++r) {
            int row = bm * 32 + wm * 16 + lq * 4 + r;
            nm[(size_t)row * 512 + col] = acc[ni][r] + bv;
        }
    }
}

// ---------------------------------------------------------------------------
// t=0: es = lrelu(nm_i + nm_j + em0_b), write es, agg -> fused node update
__global__ __launch_bounds__(256) void edge_rank1(
    const float* __restrict__ nm, const float* __restrict__ em0,
    const int* __restrict__ mask,
    __hip_bfloat16* __restrict__ es_dst,
    const float* __restrict__ denom,
    float* __restrict__ nodef, __hip_bfloat16* __restrict__ nodeb)
{
    int g = blockIdx.x >> 1, ch = blockIdx.x & 1;
    int c = ch * 256 + threadIdx.x;
    int b = g >> 6;
    float nmi = nm[(size_t)g * 512 + c];          // raw nm[g][c]
    float emb = em0[b * 512 + c];
    const float* nmb = nm + (size_t)b * 64 * 512;
    const int* mrow = mask + g * 64;
    __hip_bfloat16* erow = es_dst + (size_t)g * 64 * 512 + c;
    float aggv = 0.f;
#pragma unroll 4
    for (int j = 0; j < 64; ++j) {
        float nmj = nmb[j * 512 + c];
        float es = lrelu(nmi + nmj + emb);
        erow[(size_t)j * 512] = __float2bfloat16(es);
        aggv += es * nmj * (float)mrow[j];
    }
    float nf = (nmi + aggv) / denom[g];
    size_t idx = (size_t)g * 512 + c;
    float ns = nodef[idx] + lrelu(nf);
    nodef[idx] = ns;
    nodeb[idx] = __float2bfloat16(ns);
}

// ---------------------------------------------------------------------------
// Fused edge GEMM + epilogue + node update for t>=1.  BM=BN=64, BK=64.
// Occupancy-first redesign: wave owns 64 j-rows x 16 cols -> acc[4][1] = 16
// accumulator VGPRs (vs 64 in the 128x128 tile); LDS 16 KB/block;
// __launch_bounds__(256,6) caps VGPR at 85 -> 6 blocks / 24 waves per CU
// (1.5x round-4) and 4096 blocks = 16 generations/CU. The only lever that
// has EVER moved this kernel (r0->r4) is resident-wave count; this buys the
// maximum of it without touching the proven sync structure (stage -> sync ->
// compute -> sync, single-buffered).
// Grid (bm=512, bn=8): hardware round-robin XCD = id%8 = bm%8, so the 8
// bn-siblings sharing one es row-panel land on ONE XCD's L2; eW (0.5 MB)
// fits every L2.
__global__ __launch_bounds__(256, 6) void edge_fused(
    const __hip_bfloat16* __restrict__ es_src,   // 32768 x 512 bf16
    const __hip_bfloat16* __restrict__ eW,       // 512 x 512 bf16 (o,h)
    const float* __restrict__ eB,                // 512 fp32
    const float* __restrict__ nm,                // 512 x 512 fp32
    const int* __restrict__ mask,                // 8*64*64
    __hip_bfloat16* __restrict__ es_dst,
    const float* __restrict__ denom,
    float* __restrict__ nodef, __hip_bfloat16* __restrict__ nodeb,
    int write_es)
{
    __shared__ __align__(16) __hip_bfloat16 sA[64 * 64];   // 8 KB
    __shared__ __align__(16) __hip_bfloat16 sB[64 * 64];   // 8 KB
    int tid = threadIdx.x;
    int bm = blockIdx.x;             // 0..511 : g (one 64-row group per block)
    int bn = blockIdx.y;             // 0..7   : 64-col slice of eW
    int w = tid >> 6, l = tid & 63;
    int lq = l >> 4, lr = l & 15;

    const char* aBase = (const char*)es_src + (size_t)bm * 64 * 1024;  // row 1024B
    const char* bBase = (const char*)eW + (size_t)bn * 64 * 1024;
    // staging: 512 chunks of 16B per matrix per kt; thread t -> chunks t, t+256.
    // chunk c: row = c>>3, c16 = c&7; source col pre-swizzled (c16 ^ row&7),
    // LDS dest linear (rule #21); reads apply the same XOR.
    int rrow = tid >> 3;
    int gOff = rrow * 1024 + ((((tid & 7) ^ (rrow & 7))) << 4);
    int lOff = tid * 16;
    int sw = lr & 7;

    f32x4 acc[4] = {};

    for (int kt = 0; kt < 8; ++kt) {
        int ko = kt * 128;   // 64 cols * 2B
        cp16(aBase + gOff + ko,         (char*)sA + lOff);
        cp16(aBase + gOff + 32768 + ko, (char*)sA + lOff + 4096);
        cp16(bBase + gOff + ko,         (char*)sB + lOff);
        cp16(bBase + gOff + 32768 + ko, (char*)sB + lOff + 4096);
        __syncthreads();
#pragma unroll
        for (int kk = 0; kk < 2; ++kk) {
            bf16x8 bf = *(const bf16x8*)&sB[(w * 16 + lr) * 64 + (((kk * 4 + lq) ^ sw) << 3)];
#pragma unroll
            for (int mi = 0; mi < 4; ++mi) {
                bf16x8 af = *(const bf16x8*)&sA[(mi * 16 + lr) * 64 + (((kk * 4 + lq) ^ sw) << 3)];
                acc[mi] = __builtin_amdgcn_mfma_f32_16x16x32_bf16(af, bf, acc[mi], 0, 0, 0);
            }
        }
        __syncthreads();
    }

    // Epilogue: wave owns (g = bm, all 64 j) x 16 cols (c = bn*64 + w*16 + lr)
    int g = bm;
    int b = g >> 6;
    int c = bn * 64 + w * 16 + lr;

    float nmraw = nm[(size_t)g * 512 + c];
    float nmi = nmraw + eB[c];
    const float* nmb = nm + (size_t)b * 64 * 512;
    const int* mrow = mask + g * 64;
    float aggv = 0.f;

#pragma unroll
    for (int mi = 0; mi < 4; ++mi) {
#pragma unroll
        for (int r = 0; r < 4; ++r) {
            int j = mi * 16 + lq * 4 + r;
            float mf = (float)mrow[j];
            float nmj = nmb[(size_t)j * 512 + c];
            float es = lrelu(acc[mi][r] + nmi + nmj);
            if (write_es) es_dst[((size_t)(g * 64 + j)) * 512 + c] = __float2bfloat16(es);
            aggv += es * nmj * mf;
        }
    }
    aggv += __shfl_xor(aggv, 16, 64);
    aggv += __shfl_xor(aggv, 32, 64);
    if (lq == 0) {
        size_t oidx = (size_t)g * 512 + c;
        float nf = (nmraw + aggv) / denom[g];
        float ns = nodef[oidx] + lrelu(nf);
        nodef[oidx] = ns;
        nodeb[oidx] = __float2bfloat16(ns);
    }
}

// ---------------------------------------------------------------------------
// out (fp32): out[b,i,j,0:512]=node[b,i,:], [512:1024]=node[b,j,:]
__global__ __launch_bounds__(256) void out_kernel(
    const float* __restrict__ nodef, float* __restrict__ out)
{
    size_t ch = (size_t)blockIdx.x * 256 + threadIdx.x;  // 16B chunk id
    int c4 = (int)(ch & 255);
    size_t r = ch >> 8;                // (b*64+i)*64 + j
    int b = (int)(r >> 12);
    int i = (int)((r >> 6) & 63);
    int j = (int)(r & 63);
    int c = c4 * 4;
    const float* src = (c < 512) ? (nodef + ((size_t)(b * 64 + i)) * 512 + c)
                                 : (nodef + ((size_t)(b * 64 + j)) * 512 + (c - 512));
    *reinterpret_cast<float4*>(out + ch * 4) = *reinterpret_cast<const float4*>(src);
}

// ---------------------------------------------------------------------------
extern "C" void kernel_launch(void* const* d_in, const int* in_sizes, int n_in,
                              void* d_out, int out_size, void* d_ws, size_t ws_size,
                              hipStream_t stream) {
    const float* roi  = (const float*)d_in[0];
    const float* img  = (const float*)d_in[1];
    const float* nW   = (const float*)d_in[2];
    const float* nB   = (const float*)d_in[3];
    const float* eW   = (const float*)d_in[4];
    const float* eB   = (const float*)d_in[5];
    const int*   mask = (const int*)d_in[6];

    // Large scratch inside d_out; all dead before out_kernel rewrites.
    char* ob = (char*)d_out;
    const size_t ES_BYTES = (size_t)32768 * 512 * 2;            // 33,554,432
    __hip_bfloat16* es0   = (__hip_bfloat16*)(ob);
    __hip_bfloat16* es1   = (__hip_bfloat16*)(ob + ES_BYTES);
    __hip_bfloat16* eWb   = (__hip_bfloat16*)(ob + 2 * ES_BYTES);              // 2.62MB
    __hip_bfloat16* nWb   = (__hip_bfloat16*)(ob + 2 * ES_BYTES + 2621440);    // 2.62MB
    __hip_bfloat16* nodeb = (__hip_bfloat16*)(ob + 2 * ES_BYTES + 5242880);    // 0.5MB
    float*          nm    = (float*)(ob + 2 * ES_BYTES + 5767168);             // 1MB
    float*       edge_init= (float*)(ob + 2 * ES_BYTES + 6815744);             // 16KB
    float*          em0   = (float*)(ob + 2 * ES_BYTES + 6832128);             // 16KB

    char* ws = (char*)d_ws;
    float* nodef = (float*)(ws);                 // 1MB
    float* denom = (float*)(ws + 1048576);       // 2KB
    float* outp  = (float*)d_out;

    prep_kernel<<<3842, 256, 0, stream>>>(roi, img, nW, eW, mask,
                                          nWb, eWb, nodef, nodeb, edge_init, denom);
    em0_kernel<<<1024, 256, 0, stream>>>(edge_init, eW, eB, em0);

    // t = 0
    nm_gemm<<<dim3(16, 8), 256, 0, stream>>>(nodeb, nWb, nB, nm);
    edge_rank1<<<1024, 256, 0, stream>>>(nm, em0, mask, es0, denom, nodef, nodeb);

    // t = 1..4
    for (int t = 1; t < NLAYER; ++t) {
        const __hip_bfloat16* src = (t & 1) ? es0 : es1;
        __hip_bfloat16* dst       = (t & 1) ? es1 : es0;
        nm_gemm<<<dim3(16, 8), 256, 0, stream>>>(nodeb, nWb + (size_t)t * 262144,
                                                 nB + t * 512, nm);
        edge_fused<<<dim3(512, 8), 256, 0, stream>>>(src, eWb + (size_t)t * 262144,
                                                     eB + t * 512, nm, mask,
                                                     dst, denom, nodef, nodeb,
                                                     (t < 4) ? 1 : 0);
    }

    out_kernel<<<32768, 256, 0, stream>>>(nodef, outp);
}